// Round 1
// baseline (692.471 us; speedup 1.0000x reference)
//
#include <hip/hip_runtime.h>
#include <math.h>

#define D 128
#define WAVE 64

// ---------------- CSR build ----------------

__global__ void zero_i32(int* __restrict__ p, int n) {
    int i = blockIdx.x * 256 + threadIdx.x;
    if (i < n) p[i] = 0;
}

__global__ void hist_kernel(const int* __restrict__ dst, int E, int* __restrict__ counts) {
    int e = blockIdx.x * 256 + threadIdx.x;
    if (e < E) atomicAdd(&counts[dst[e]], 1);
}

// block scans 1024 elements (256 thr x 4). Writes inclusive scan to row_ptr[i+1], block total to bsums.
__global__ __launch_bounds__(256) void scan_k1(const int* __restrict__ counts, int n,
                                               int* __restrict__ row_ptr, int* __restrict__ bsums) {
    __shared__ int wsum[4];
    int tid = threadIdx.x;
    int base = blockIdx.x * 1024 + tid * 4;
    int4 v = make_int4(0, 0, 0, 0);
    if (base < n) v = *(const int4*)(counts + base);   // n % 4 == 0 guaranteed (100000)
    int s = v.x + v.y + v.z + v.w;
    int lane = tid & 63;
    int incl = s;
    #pragma unroll
    for (int off = 1; off < 64; off <<= 1) {
        int t = __shfl_up(incl, off);
        if (lane >= off) incl += t;
    }
    int wv = tid >> 6;
    if (lane == 63) wsum[wv] = incl;
    __syncthreads();
    int woff = 0;
    for (int w = 0; w < wv; w++) woff += wsum[w];
    int excl = woff + incl - s;
    if (base < n) {
        row_ptr[base + 1] = excl + v.x;
        row_ptr[base + 2] = excl + v.x + v.y;
        row_ptr[base + 3] = excl + v.x + v.y + v.z;
        row_ptr[base + 4] = excl + v.x + v.y + v.z + v.w;
    }
    if (tid == 255) bsums[blockIdx.x] = woff + incl;
}

// single wave, exclusive-scan bsums in place
__global__ void scan_k2(int* __restrict__ bsums, int nb) {
    int lane = threadIdx.x;
    int carry = 0;
    for (int base = 0; base < nb; base += 64) {
        int i = base + lane;
        int v = (i < nb) ? bsums[i] : 0;
        int incl = v;
        #pragma unroll
        for (int off = 1; off < 64; off <<= 1) {
            int t = __shfl_up(incl, off);
            if (lane >= off) incl += t;
        }
        int excl = incl - v + carry;
        if (i < nb) bsums[i] = excl;
        carry += __shfl(incl, 63);
    }
}

// add block offsets; convert counts -> cursor (exclusive start per node)
__global__ void scan_k3(int* __restrict__ row_ptr, int* __restrict__ counts,
                        const int* __restrict__ bsums, int n) {
    int i = blockIdx.x * 256 + threadIdx.x;
    if (i >= n) return;
    int off = bsums[i >> 10];
    int incl = row_ptr[i + 1] + off;
    row_ptr[i + 1] = incl;
    counts[i] = incl - counts[i];   // exclusive start == cursor
    if (i == 0) row_ptr[0] = 0;
}

__global__ void scatter_edges(const int* __restrict__ src, const int* __restrict__ dst, int E,
                              int* __restrict__ cursor, int* __restrict__ col_idx) {
    int e = blockIdx.x * 256 + threadIdx.x;
    if (e >= E) return;
    int d = dst[e];
    int p = atomicAdd(&cursor[d], 1);
    col_idx[p] = src[e];
}

// exclusive scan of graph sizes (G <= 1024), single block of 256
__global__ __launch_bounds__(256) void goff_scan(const int* __restrict__ gsz, int G, int* __restrict__ goff) {
    __shared__ int wsum[4];
    int tid = threadIdx.x;
    int base = tid * 4;
    int a = base + 0 < G ? gsz[base + 0] : 0;
    int b = base + 1 < G ? gsz[base + 1] : 0;
    int c = base + 2 < G ? gsz[base + 2] : 0;
    int d = base + 3 < G ? gsz[base + 3] : 0;
    int s = a + b + c + d;
    int lane = tid & 63;
    int incl = s;
    #pragma unroll
    for (int off = 1; off < 64; off <<= 1) {
        int t = __shfl_up(incl, off);
        if (lane >= off) incl += t;
    }
    int wv = tid >> 6;
    if (lane == 63) wsum[wv] = incl;
    __syncthreads();
    int woff = 0;
    for (int w = 0; w < wv; w++) woff += wsum[w];
    int excl = woff + incl - s;
    if (base + 0 < G) goff[base + 0] = excl;
    if (base + 1 < G) goff[base + 1] = excl + a;
    if (base + 2 < G) goff[base + 2] = excl + a + b;
    if (base + 3 < G) goff[base + 3] = excl + a + b + c;
}

// ---------------- dense GEMM: out[N][128] = A[N][128] @ W[128][128] ----------------
// block: 64 rows x 64 cols (blockIdx.y selects col half). 256 threads, 4x4 per thread.
// LDS exactly 64 KiB: Xs 64x128 + Ws 128x64 (W read is 2-way bank alias = free;
// X read is 4-way, acceptable round 1 — hidden under FMA issue).
__global__ __launch_bounds__(256, 2) void gemm128(const float* __restrict__ A, const float* __restrict__ W,
                                                  float* __restrict__ out, int N) {
    __shared__ float Xs[64 * 128];
    __shared__ float Ws[128 * 64];
    const int tid = threadIdx.x;
    const int row0 = blockIdx.x * 64;
    const int c0 = blockIdx.y * 64;
    for (int i = tid; i < 128 * 16; i += 256) {          // stage W half: 2048 float4
        int k = i >> 4;
        int c4 = (i & 15) * 4;
        *(float4*)(Ws + k * 64 + c4) = *(const float4*)(W + k * 128 + c0 + c4);
    }
    for (int i = tid; i < 64 * 32; i += 256) {           // stage X tile: 2048 float4
        int r = i >> 5;
        int k4 = (i & 31) * 4;
        int gr = row0 + r;
        float4 v = make_float4(0.f, 0.f, 0.f, 0.f);
        if (gr < N) v = *(const float4*)(A + gr * 128 + k4);
        *(float4*)(Xs + r * 128 + k4) = v;
    }
    __syncthreads();
    const int tx = tid & 15;
    const int ty = tid >> 4;
    const int rbase = ty * 4;
    const int cbase = tx * 4;
    float acc[4][4] = {};
    #pragma unroll 4
    for (int k = 0; k < 128; k += 4) {
        float4 xv[4], wv[4];
        #pragma unroll
        for (int r = 0; r < 4; r++) xv[r] = *(const float4*)(Xs + (rbase + r) * 128 + k);
        #pragma unroll
        for (int kk = 0; kk < 4; kk++) wv[kk] = *(const float4*)(Ws + (k + kk) * 64 + cbase);
        #pragma unroll
        for (int r = 0; r < 4; r++) {
            const float* xr = (const float*)&xv[r];
            #pragma unroll
            for (int kk = 0; kk < 4; kk++) {
                float x = xr[kk];
                acc[r][0] += x * wv[kk].x;
                acc[r][1] += x * wv[kk].y;
                acc[r][2] += x * wv[kk].z;
                acc[r][3] += x * wv[kk].w;
            }
        }
    }
    #pragma unroll
    for (int r = 0; r < 4; r++) {
        int gr = row0 + rbase + r;
        if (gr < N)
            *(float4*)(out + gr * 128 + c0 + cbase) =
                make_float4(acc[r][0], acc[r][1], acc[r][2], acc[r][3]);
    }
}

// ---------------- aggregate: out[i] = relu(xw[i] + b + sum_{j in CSR[i]} xw[j]) ----------------
// one wave per node; lane holds float2 slice of the 128-dim row.
__global__ __launch_bounds__(256) void agg_relu(const float* __restrict__ xw, const int* __restrict__ row_ptr,
                                                const int* __restrict__ col_idx, const float* __restrict__ bias,
                                                float* __restrict__ outp, int N) {
    int wid = (blockIdx.x * 256 + threadIdx.x) >> 6;
    int lane = threadIdx.x & 63;
    if (wid >= N) return;
    float2 b = *(const float2*)(bias + lane * 2);
    float2 acc = *(const float2*)(xw + wid * D + lane * 2);
    acc.x += b.x; acc.y += b.y;
    int start = row_ptr[wid], end = row_ptr[wid + 1];
    for (int e = start; e < end; e += 64) {
        int myе = e + lane;
        int j = (myе < end) ? col_idx[myе] : 0;
        int cnt = min(64, end - e);
        int i = 0;
        for (; i + 1 < cnt; i += 2) {
            int j0 = __shfl(j, i), j1 = __shfl(j, i + 1);
            float2 v0 = *(const float2*)(xw + j0 * D + lane * 2);
            float2 v1 = *(const float2*)(xw + j1 * D + lane * 2);
            acc.x += v0.x + v1.x;
            acc.y += v0.y + v1.y;
        }
        if (i < cnt) {
            int j0 = __shfl(j, i);
            float2 v0 = *(const float2*)(xw + j0 * D + lane * 2);
            acc.x += v0.x;
            acc.y += v0.y;
        }
    }
    acc.x = fmaxf(acc.x, 0.f);
    acc.y = fmaxf(acc.y, 0.f);
    *(float2*)(outp + wid * D + lane * 2) = acc;
}

// ---------------- head: out12[n][12] = sigmoid(h[n] @ Wf + bf) ----------------
__global__ __launch_bounds__(256) void head_sigmoid(const float* __restrict__ h, const float* __restrict__ Wf,
                                                    const float* __restrict__ bfv, float* __restrict__ out12, int N) {
    __shared__ float Wl[128 * 12];
    __shared__ float bl[12];
    for (int i = threadIdx.x; i < 128 * 12; i += 256) Wl[i] = Wf[i];
    if (threadIdx.x < 12) bl[threadIdx.x] = bfv[threadIdx.x];
    __syncthreads();
    int node = blockIdx.x * 256 + threadIdx.x;
    if (node >= N) return;
    float acc[12];
    #pragma unroll
    for (int t = 0; t < 12; t++) acc[t] = bl[t];
    const float* hr = h + (size_t)node * D;
    for (int k = 0; k < 128; k += 4) {
        float4 hv = *(const float4*)(hr + k);
        const float* hx = (const float*)&hv;
        #pragma unroll
        for (int kk = 0; kk < 4; kk++) {
            float x = hx[kk];
            const float* wr = Wl + (k + kk) * 12;
            #pragma unroll
            for (int t = 0; t < 12; t++) acc[t] += x * wr[t];
        }
    }
    float* o = out12 + (size_t)node * 12;
    #pragma unroll
    for (int t = 0; t < 12; t++) o[t] = 1.f / (1.f + __expf(-acc[t]));
}

// ---------------- per-graph mean ----------------
__global__ __launch_bounds__(128) void graph_mean(const float* __restrict__ out12, const int* __restrict__ goff,
                                                  const int* __restrict__ gsize, float* __restrict__ out, int G) {
    __shared__ float partial[120];
    int g = blockIdx.x;
    int tid = threadIdx.x;
    int start = goff[g];
    int size = gsize[g];
    if (tid < 120) {
        int t = tid % 12, chunk = tid / 12;
        float s = 0.f;
        for (int i = chunk; i < size; i += 10)
            s += out12[(size_t)(start + i) * 12 + t];
        partial[tid] = s;
    }
    __syncthreads();
    if (tid < 12) {
        float tot = 0.f;
        #pragma unroll
        for (int c = 0; c < 10; c++) tot += partial[c * 12 + tid];
        out[g * 12 + tid] = tot / (float)size;
    }
}

// ---------------- launch ----------------

extern "C" void kernel_launch(void* const* d_in, const int* in_sizes, int n_in,
                              void* d_out, int out_size, void* d_ws, size_t ws_size,
                              hipStream_t stream) {
    const float* X   = (const float*)d_in[0];
    const int* edges = (const int*)d_in[1];
    const int* gsz   = (const int*)d_in[2];
    const float* W0  = (const float*)d_in[3];
    const float* b0  = (const float*)d_in[4];
    const float* W1  = (const float*)d_in[5];
    const float* b1  = (const float*)d_in[6];
    const float* Wf  = (const float*)d_in[7];
    const float* bfv = (const float*)d_in[8];
    float* out = (float*)d_out;

    const int N = in_sizes[0] / D;       // 100000
    const int E = in_sizes[1] / 2;       // 1600000
    const int G = in_sizes[2];           // 1000
    const int* esrc = edges;
    const int* edst = edges + E;

    // workspace layout (bytes)
    char* ws = (char*)d_ws;
    float* xw      = (float*)(ws);                                   // N*128 f32 = 51.2 MB
    float* hbuf    = (float*)(ws + (size_t)N * D * 4);               // 51.2 MB
    float* out12   = (float*)(ws + (size_t)2 * N * D * 4);           // N*12 f32 = 4.8 MB
    char*  p       = ws + (size_t)2 * N * D * 4 + (size_t)N * 12 * 4;
    int* row_ptr   = (int*)p;            p += ((size_t)(N + 1) * 4 + 255) & ~255ull;
    int* counts    = (int*)p;            p += ((size_t)N * 4 + 255) & ~255ull;
    int* bsums     = (int*)p;            p += 4096;
    int* goff      = (int*)p;            p += 4096;
    int* col_idx   = (int*)p;

    const int nScanBlocks = (N + 1023) / 1024;

    // CSR build
    zero_i32<<<(N + 255) / 256, 256, 0, stream>>>(counts, N);
    hist_kernel<<<(E + 255) / 256, 256, 0, stream>>>(edst, E, counts);
    scan_k1<<<nScanBlocks, 256, 0, stream>>>(counts, N, row_ptr, bsums);
    scan_k2<<<1, 64, 0, stream>>>(bsums, nScanBlocks);
    scan_k3<<<(N + 255) / 256, 256, 0, stream>>>(row_ptr, counts, bsums, N);
    scatter_edges<<<(E + 255) / 256, 256, 0, stream>>>(esrc, edst, E, counts, col_idx);

    // graph offsets
    goff_scan<<<1, 256, 0, stream>>>(gsz, G, goff);

    dim3 ggrid((N + 63) / 64, 2);
    // layer 0
    gemm128<<<ggrid, 256, 0, stream>>>(X, W0, xw, N);
    agg_relu<<<(N * 64 + 255) / 256, 256, 0, stream>>>(xw, row_ptr, col_idx, b0, hbuf, N);
    // layer 1
    gemm128<<<ggrid, 256, 0, stream>>>(hbuf, W1, xw, N);
    agg_relu<<<(N * 64 + 255) / 256, 256, 0, stream>>>(xw, row_ptr, col_idx, b1, hbuf, N);
    // head + readout
    head_sigmoid<<<(N + 255) / 256, 256, 0, stream>>>(hbuf, Wf, bfv, out12, N);
    graph_mean<<<G, 128, 0, stream>>>(out12, goff, gsz, out, G);
}